// Round 7
// baseline (216.367 us; speedup 1.0000x reference)
//
#include <hip/hip_runtime.h>
#include <hip/hip_fp16.h>

typedef _Float16 f16;
typedef __attribute__((ext_vector_type(8))) _Float16 f16x8;
typedef __attribute__((ext_vector_type(4))) _Float16 f16x4;
typedef __attribute__((ext_vector_type(4))) float f32x4;

#define MFMA16(a, b, c) __builtin_amdgcn_mfma_f32_16x16x32_f16((a), (b), (c), 0, 0, 0)

// ---------------- workspace layout (bytes) ----------------
#define OFF_WK   0u              // w_k folded f16 [256][256]
#define OFF_WS   131072u         // w_s folded f16 [256][256]
#define OFF_WH1  262144u         // w_h1 folded f16 [256][256]
#define OFF_W2P  393216u         // w_h2 padded f16 [32][256]
#define OFF_SH   409600u         // shifts f32 [3][256]
#define OFF_S    412672u         // Xt_s then (in-place) s feat f16 [123008][256]
#define OFF_KF   63392768u       // Xt_k then (in-place) k feat f16 [6272][256]
#define OFF_FEAT 66604032u       // xcorr out f16 [80000][256]

// ---------------- weight prep: fold BN scale, convert to f16, pad W2 ----------------
__global__ __launch_bounds__(256) void prep_weights(
    const float* __restrict__ wk, const float* __restrict__ gk, const float* __restrict__ bk,
    const float* __restrict__ mk, const float* __restrict__ vk,
    const float* __restrict__ wsr, const float* __restrict__ gs, const float* __restrict__ bs,
    const float* __restrict__ ms, const float* __restrict__ vs,
    const float* __restrict__ wh1, const float* __restrict__ gh, const float* __restrict__ bh,
    const float* __restrict__ mh, const float* __restrict__ vh,
    const float* __restrict__ wh2,
    f16* __restrict__ wk16, f16* __restrict__ ws16, f16* __restrict__ wh116,
    f16* __restrict__ w2p, float* __restrict__ shifts) {
  int o = blockIdx.x;
  int t = threadIdx.x;
  float sck = gk[o] * rsqrtf(vk[o] + 1e-5f);
  float scs = gs[o] * rsqrtf(vs[o] + 1e-5f);
  float sch = gh[o] * rsqrtf(vh[o] + 1e-5f);
  int idx = o * 256 + t;
  wk16[idx]  = (f16)(wk[idx] * sck);
  ws16[idx]  = (f16)(wsr[idx] * scs);
  wh116[idx] = (f16)(wh1[idx] * sch);
  if (o < 32) w2p[idx] = (o < 20) ? (f16)wh2[idx] : (f16)0;
  if (t == 0) {
    shifts[o]       = bk[o] - mk[o] * sck;
    shifts[256 + o] = bs[o] - ms[o] * scs;
    shifts[512 + o] = bh[o] - mh[o] * sch;
  }
}

// ---------------- pure streaming transpose: NCHW fp32 -> [b*P+p][256] f16 ----------------
// No LDS, no barriers. thread = (8 channels, 4 consecutive pixels):
// 8 coalesced float4 loads (128B runs), register transpose, 4 x 16B stores (128B runs).
template <int P>
__global__ __launch_bounds__(256) void transpose_cl(
    const float* __restrict__ X, f16* __restrict__ out) {
  int p0 = blockIdx.x * 128;
  int c0 = blockIdx.y * 64;
  int b  = blockIdx.z;
  int t = threadIdx.x;
  int cg = t & 7;           // channel group (8 ch)
  int pq = t >> 3;          // pixel quad 0..31
  int p = p0 + pq * 4;
  if (p >= P) return;
  const float* xb = X + ((size_t)b * 256 + c0 + cg * 8) * P;
  f32x4 col[8];
  if (p + 3 < P) {
#pragma unroll
    for (int j = 0; j < 8; ++j) col[j] = *(const f32x4*)(xb + (size_t)j * P + p);
  } else {
#pragma unroll
    for (int j = 0; j < 8; ++j)
#pragma unroll
      for (int e = 0; e < 4; ++e)
        col[j][e] = (p + e < P) ? xb[(size_t)j * P + p + e] : 0.0f;
  }
#pragma unroll
  for (int e = 0; e < 4; ++e) {
    if (p + e < P) {
      f16x8 v;
#pragma unroll
      for (int j = 0; j < 8; ++j) v[j] = (f16)col[j][e];
      *(f16x8*)(out + ((size_t)b * P + p + e) * 256 + c0 + cg * 8) = v;
    }
  }
}

// ---------------- channels-last f16 GEMM + BN(shift) + ReLU, IN-PLACE capable ----------
// Tile 128n x 256o, 4 waves (wave = 64 o-rows), acc 4x8. No LDS; K-loop is pure
// global b128 loads + MFMA (no barriers -> compiler pipelines ci+1 loads under MFMA).
// One __syncthreads before epilogue so out may alias Xt (blocks own disjoint 128-row
// slices; all waves' reads retire at the barrier before any store).
__global__ __launch_bounds__(256, 2) void gemm_cl(
    const f16* Xt, const f16* __restrict__ W,
    const float* __restrict__ shift, f16* out) {
  const int C = 256;
  int n0 = blockIdx.x * 128;
  int t = threadIdx.x;
  int lane = t & 63, wave = t >> 6;
  int fm = lane & 15, kg = lane >> 4;

  const f16* wp = W + (size_t)(wave * 64 + fm) * C + kg * 8;
  const f16* xp = Xt + (size_t)(n0 + fm) * C + kg * 8;

  f32x4 acc[4][8] = {};
#pragma unroll
  for (int ci = 0; ci < 8; ++ci) {
    f16x8 b[8], a[4];
#pragma unroll
    for (int nf = 0; nf < 8; ++nf)
      b[nf] = *(const f16x8*)(xp + (size_t)nf * 16 * C + ci * 32);
#pragma unroll
    for (int of = 0; of < 4; ++of)
      a[of] = *(const f16x8*)(wp + (size_t)of * 16 * C + ci * 32);
#pragma unroll
    for (int of = 0; of < 4; ++of)
#pragma unroll
      for (int nf = 0; nf < 8; ++nf)
        acc[of][nf] = MFMA16(a[of], b[nf], acc[of][nf]);
  }

  __syncthreads();   // drains vmcnt: all reads of Xt complete before in-place stores

#pragma unroll
  for (int of = 0; of < 4; ++of) {
    int orow = wave * 64 + of * 16 + kg * 4;
    f32x4 sh = *(const f32x4*)(shift + orow);
#pragma unroll
    for (int nf = 0; nf < 8; ++nf) {
      int n = n0 + nf * 16 + fm;
      f16x4 st;
#pragma unroll
      for (int r = 0; r < 4; ++r)
        st[r] = (f16)fmaxf(acc[of][nf][r] + sh[r], 0.0f);
      *(f16x4*)(out + (size_t)n * C + orow) = st;
    }
  }
}

// ---------------- depthwise xcorr, row-per-wave with register reuse ----------------
__global__ __launch_bounds__(256) void xcorr_dw_row(
    const f16* __restrict__ S /* [128][31][31][256] */,
    const f16* __restrict__ K /* [128][7][7][256] */,
    f16* __restrict__ F /* [128][25][25][256] */) {
  int id = blockIdx.x;            // 0..895, XCD-swizzled
  int x = id & 7;
  int r = id >> 3;
  int g = r % 7;
  int bq = r / 7;
  int b = bq * 8 + x;

  int wave = threadIdx.x >> 6;
  int lane = threadIdx.x & 63;
  int oi = g * 4 + wave;          // 0..27
  if (oi >= 25) return;

  const f16* Sb = S + (size_t)b * 961 * 256 + lane * 4;
  const f16* Kb = K + (size_t)b * 49 * 256 + lane * 4;

  f32x4 acc[25] = {};

  for (int di = 0; di < 7; ++di) {
    const f16* sp = Sb + (size_t)(oi + di) * 31 * 256;
    f16x4 srow[31];
#pragma unroll
    for (int j = 0; j < 31; ++j) srow[j] = *(const f16x4*)(sp + (size_t)j * 256);
    const f16* kp = Kb + (size_t)di * 7 * 256;
    f16x4 krow[7];
#pragma unroll
    for (int j = 0; j < 7; ++j) krow[j] = *(const f16x4*)(kp + (size_t)j * 256);

#pragma unroll
    for (int dj = 0; dj < 7; ++dj) {
      float k0 = (float)krow[dj][0];
      float k1 = (float)krow[dj][1];
      float k2 = (float)krow[dj][2];
      float k3 = (float)krow[dj][3];
#pragma unroll
      for (int oj = 0; oj < 25; ++oj) {
        f16x4 sv = srow[oj + dj];
        acc[oj][0] += (float)sv[0] * k0;
        acc[oj][1] += (float)sv[1] * k1;
        acc[oj][2] += (float)sv[2] * k2;
        acc[oj][3] += (float)sv[3] * k3;
      }
    }
  }

  f16* Fb = F + ((size_t)b * 625 + (size_t)oi * 25) * 256 + lane * 4;
#pragma unroll
  for (int oj = 0; oj < 25; ++oj) {
    f16x4 o;
#pragma unroll
    for (int e = 0; e < 4; ++e) o[e] = (f16)acc[oj][e];
    *(f16x4*)(Fb + (size_t)oj * 256) = o;
  }
}

// ---------------- fused head: conv1(256->256)+BN+ReLU then conv2(256->20)+bias ----------
__global__ __launch_bounds__(256) void head_fused(
    const f16* __restrict__ Xt /* feat [80000][256] */,
    const f16* __restrict__ W1, const float* __restrict__ shift,
    const f16* __restrict__ W2p /* [32][256] */, const float* __restrict__ bias,
    float* __restrict__ out /* [128][20][625] */) {
  const int C = 256;
  int n0 = blockIdx.x * 64;
  int t = threadIdx.x;
  int lane = t & 63, wave = t >> 6;
  int fm = lane & 15, kg = lane >> 4;

  __shared__ f16 Ys[32][64][8];   // y-tile chunk-major

  const f16* wp = W1 + (size_t)(wave * 64 + fm) * C + kg * 8;
  const f16* xp = Xt + (size_t)(n0 + fm) * C + kg * 8;

  f32x4 acc[4][4] = {};
#pragma unroll
  for (int c0 = 0; c0 < 256; c0 += 32) {
    f16x8 a[4], b[4];
#pragma unroll
    for (int of = 0; of < 4; ++of) a[of] = *(const f16x8*)(wp + (size_t)of * 16 * C + c0);
#pragma unroll
    for (int nf = 0; nf < 4; ++nf) b[nf] = *(const f16x8*)(xp + (size_t)nf * 16 * C + c0);
#pragma unroll
    for (int of = 0; of < 4; ++of)
#pragma unroll
      for (int nf = 0; nf < 4; ++nf)
        acc[of][nf] = MFMA16(a[of], b[nf], acc[of][nf]);
  }

#pragma unroll
  for (int of = 0; of < 4; ++of) {
    int orow = wave * 64 + of * 16 + kg * 4;
#pragma unroll
    for (int nf = 0; nf < 4; ++nf) {
      int n = nf * 16 + fm;
      f16x4 st;
#pragma unroll
      for (int r = 0; r < 4; ++r)
        st[r] = (f16)fmaxf(acc[of][nf][r] + shift[orow + r], 0.0f);
      *(f16x4*)&Ys[orow >> 3][n][(kg & 1) * 4] = st;
    }
  }
  __syncthreads();

  // GEMM2: M=32 (20 live), N=64 (wave -> 16 n), K=256
  f32x4 acc2[2] = {};
#pragma unroll
  for (int c0 = 0; c0 < 256; c0 += 32) {
    f16x8 b = *(const f16x8*)&Ys[(c0 >> 3) + kg][wave * 16 + fm][0];
    f16x8 a0 = *(const f16x8*)(W2p + (size_t)fm * C + c0 + kg * 8);
    f16x8 a1 = *(const f16x8*)(W2p + (size_t)(16 + fm) * C + c0 + kg * 8);
    acc2[0] = MFMA16(a0, b, acc2[0]);
    acc2[1] = MFMA16(a1, b, acc2[1]);
  }

  int n = n0 + wave * 16 + fm;
  int bq = n / 625, bp = n - bq * 625;
  float* op = out + (size_t)bq * 12500 + bp;
#pragma unroll
  for (int of = 0; of < 2; ++of) {
#pragma unroll
    for (int r = 0; r < 4; ++r) {
      int o = of * 16 + kg * 4 + r;
      if (o < 20) op[(size_t)o * 625] = acc2[of][r] + bias[o];
    }
  }
}

extern "C" void kernel_launch(void* const* d_in, const int* in_sizes, int n_in,
                              void* d_out, int out_size, void* d_ws, size_t ws_size,
                              hipStream_t stream) {
  const float* kernel_in = (const float*)d_in[0];
  const float* search    = (const float*)d_in[1];
  const float* w_k = (const float*)d_in[2];
  const float* g_k = (const float*)d_in[3];
  const float* b_k = (const float*)d_in[4];
  const float* m_k = (const float*)d_in[5];
  const float* v_k = (const float*)d_in[6];
  const float* w_s = (const float*)d_in[7];
  const float* g_s = (const float*)d_in[8];
  const float* b_s = (const float*)d_in[9];
  const float* m_s = (const float*)d_in[10];
  const float* v_s = (const float*)d_in[11];
  const float* w_h1 = (const float*)d_in[12];
  const float* g_h = (const float*)d_in[13];
  const float* b_h = (const float*)d_in[14];
  const float* m_h = (const float*)d_in[15];
  const float* v_h = (const float*)d_in[16];
  const float* w_h2 = (const float*)d_in[17];
  const float* bias_h2 = (const float*)d_in[18];
  float* out = (float*)d_out;

  char* ws = (char*)d_ws;
  f16* wk16  = (f16*)(ws + OFF_WK);
  f16* ws16  = (f16*)(ws + OFF_WS);
  f16* wh116 = (f16*)(ws + OFF_WH1);
  f16* w2p   = (f16*)(ws + OFF_W2P);
  float* shifts = (float*)(ws + OFF_SH);
  f16* sbuf = (f16*)(ws + OFF_S);     // Xt_s -> (in-place) s feat
  f16* kbuf = (f16*)(ws + OFF_KF);    // Xt_k -> (in-place) k feat
  f16* fbuf = (f16*)(ws + OFF_FEAT);

  prep_weights<<<256, 256, 0, stream>>>(w_k, g_k, b_k, m_k, v_k,
                                        w_s, g_s, b_s, m_s, v_s,
                                        w_h1, g_h, b_h, m_h, v_h, w_h2,
                                        wk16, ws16, wh116, w2p, shifts);

  // streaming NCHW->channels-last f16 transposes
  transpose_cl<961><<<dim3(8, 4, 128), 256, 0, stream>>>(search, sbuf);
  transpose_cl<49><<<dim3(1, 4, 128), 256, 0, stream>>>(kernel_in, kbuf);

  // channels-last GEMMs, in-place (feat overwrites Xt), 128n per block
  gemm_cl<<<dim3(961), 256, 0, stream>>>(sbuf, ws16, shifts + 256, sbuf);
  gemm_cl<<<dim3(49), 256, 0, stream>>>(kbuf, wk16, shifts + 0, kbuf);

  // depthwise xcorr
  xcorr_dw_row<<<dim3(896), 256, 0, stream>>>(sbuf, kbuf, fbuf);

  // fused head: conv1+BN+ReLU+conv2+bias -> fp32 NCHW
  head_fused<<<dim3(1250), 256, 0, stream>>>(
      fbuf, wh116, shifts + 512, w2p, bias_h2, out);
}

// Round 8
// 191.017 us; speedup vs baseline: 1.1327x; 1.1327x over previous
//
#include <hip/hip_runtime.h>
#include <hip/hip_fp16.h>

typedef _Float16 f16;
typedef __attribute__((ext_vector_type(8))) _Float16 f16x8;
typedef __attribute__((ext_vector_type(4))) _Float16 f16x4;
typedef __attribute__((ext_vector_type(4))) float f32x4;

#define MFMA16(a, b, c) __builtin_amdgcn_mfma_f32_16x16x32_f16((a), (b), (c), 0, 0, 0)

// ---------------- workspace layout (bytes); ws_size ~480 MB (observed poison fill) ----
#define OFF_WK   0u              // w_k folded f16 [256][256]
#define OFF_WS   131072u         // w_s folded f16 [256][256]
#define OFF_WH1  262144u         // w_h1 folded f16 [256][256]
#define OFF_W2P  393216u         // w_h2 padded f16 [32][256]
#define OFF_SH   409600u         // shifts f32 [3][256]
#define OFF_S    412672u         // Xt_s f16 [123008][256]   (62,980,096 B)
#define OFF_KF   63392768u       // Xt_k f16 [6272][256]     (3,211,264 B)
#define OFF_FEAT 66604032u       // xcorr out f16 [80000][256] (40,960,000 B)
#define OFF_S2   107564032u      // s feat f16 [123008][256] (62,980,096 B)
#define OFF_KF2  170544128u      // k feat f16 [6272][256]   (3,211,264 B)

// ---------------- weight prep: fold BN scale, convert to f16, pad W2 ----------------
__global__ __launch_bounds__(256) void prep_weights(
    const float* __restrict__ wk, const float* __restrict__ gk, const float* __restrict__ bk,
    const float* __restrict__ mk, const float* __restrict__ vk,
    const float* __restrict__ wsr, const float* __restrict__ gs, const float* __restrict__ bs,
    const float* __restrict__ ms, const float* __restrict__ vs,
    const float* __restrict__ wh1, const float* __restrict__ gh, const float* __restrict__ bh,
    const float* __restrict__ mh, const float* __restrict__ vh,
    const float* __restrict__ wh2,
    f16* __restrict__ wk16, f16* __restrict__ ws16, f16* __restrict__ wh116,
    f16* __restrict__ w2p, float* __restrict__ shifts) {
  int o = blockIdx.x;
  int t = threadIdx.x;
  float sck = gk[o] * rsqrtf(vk[o] + 1e-5f);
  float scs = gs[o] * rsqrtf(vs[o] + 1e-5f);
  float sch = gh[o] * rsqrtf(vh[o] + 1e-5f);
  int idx = o * 256 + t;
  wk16[idx]  = (f16)(wk[idx] * sck);
  ws16[idx]  = (f16)(wsr[idx] * scs);
  wh116[idx] = (f16)(wh1[idx] * sch);
  if (o < 32) w2p[idx] = (o < 20) ? (f16)wh2[idx] : (f16)0;
  if (t == 0) {
    shifts[o]       = bk[o] - mk[o] * sck;
    shifts[256 + o] = bs[o] - ms[o] * scs;
    shifts[512 + o] = bh[o] - mh[o] * sch;
  }
}

// ---------------- pure streaming transpose: NCHW fp32 -> [b*P+p][256] f16 ----------------
template <int P>
__global__ __launch_bounds__(256) void transpose_cl(
    const float* __restrict__ X, f16* __restrict__ out) {
  int p0 = blockIdx.x * 128;
  int c0 = blockIdx.y * 64;
  int b  = blockIdx.z;
  int t = threadIdx.x;
  int cg = t & 7;           // channel group (8 ch)
  int pq = t >> 3;          // pixel quad 0..31
  int p = p0 + pq * 4;
  if (p >= P) return;
  const float* xb = X + ((size_t)b * 256 + c0 + cg * 8) * P;
  f32x4 col[8];
  if (p + 3 < P) {
#pragma unroll
    for (int j = 0; j < 8; ++j) col[j] = *(const f32x4*)(xb + (size_t)j * P + p);
  } else {
#pragma unroll
    for (int j = 0; j < 8; ++j)
#pragma unroll
      for (int e = 0; e < 4; ++e)
        col[j][e] = (p + e < P) ? xb[(size_t)j * P + p + e] : 0.0f;
  }
#pragma unroll
  for (int e = 0; e < 4; ++e) {
    if (p + e < P) {
      f16x8 v;
#pragma unroll
      for (int j = 0; j < 8; ++j) v[j] = (f16)col[j][e];
      *(f16x8*)(out + ((size_t)b * P + p + e) * 256 + c0 + cg * 8) = v;
    }
  }
}

// ---------------- LDS GEMM (m97-style): 128o x 128n tile, BK=32, reg-staged dbuf LDS ----
// 4 waves (2x2), acc 4x4 of 16x16x32 fragments. One barrier per K-step; next K-step's
// global loads issued before the barrier (latency hides under MFMA). B staged once per
// block (was 4x per wave in R7's gemm_cl). Not in-place (out != Xt).
__global__ __launch_bounds__(256) void gemm_lds(
    const f16* __restrict__ Xt, const f16* __restrict__ W,
    const float* __restrict__ shift, f16* __restrict__ out) {
  const int C = 256;
  int o0 = (blockIdx.x & 1) * 128;
  int n0 = (blockIdx.x >> 1) * 128;
  int t = threadIdx.x;
  int lane = t & 63, wave = t >> 6;
  int fm = lane & 15, kg = lane >> 4;
  int wr = wave >> 1, wc = wave & 1;

  __shared__ f16 As[2][4096];   // [buf][128 rows x 32 k], 8 KB each
  __shared__ f16 Bs[2][4096];

  // staging coords: thread -> (row = t>>2 plus 0/64, k-chunk = (t&3)*8); lane-linear LDS
  int srow = t >> 2;
  int sk   = (t & 3) * 8;
  const f16* ag0 = W  + (size_t)(o0 + srow) * C + sk;
  const f16* ag1 = W  + (size_t)(o0 + 64 + srow) * C + sk;
  const f16* bg0 = Xt + (size_t)(n0 + srow) * C + sk;
  const f16* bg1 = Xt + (size_t)(n0 + 64 + srow) * C + sk;

  f16x8 va0 = *(const f16x8*)ag0, va1 = *(const f16x8*)ag1;
  f16x8 vb0 = *(const f16x8*)bg0, vb1 = *(const f16x8*)bg1;

  f32x4 acc[4][4] = {};
#pragma unroll
  for (int ci = 0; ci < 8; ++ci) {
    int bsel = ci & 1;
    *(f16x8*)&As[bsel][t * 8]        = va0;
    *(f16x8*)&As[bsel][2048 + t * 8] = va1;
    *(f16x8*)&Bs[bsel][t * 8]        = vb0;
    *(f16x8*)&Bs[bsel][2048 + t * 8] = vb1;
    if (ci < 7) {                         // issue next K-step's loads early
      va0 = *(const f16x8*)(ag0 + (ci + 1) * 32);
      va1 = *(const f16x8*)(ag1 + (ci + 1) * 32);
      vb0 = *(const f16x8*)(bg0 + (ci + 1) * 32);
      vb1 = *(const f16x8*)(bg1 + (ci + 1) * 32);
    }
    __syncthreads();
    f16x8 a[4], b[4];
#pragma unroll
    for (int of = 0; of < 4; ++of)
      a[of] = *(const f16x8*)&As[bsel][(wr * 64 + of * 16 + fm) * 32 + kg * 8];
#pragma unroll
    for (int nf = 0; nf < 4; ++nf)
      b[nf] = *(const f16x8*)&Bs[bsel][(wc * 64 + nf * 16 + fm) * 32 + kg * 8];
#pragma unroll
    for (int of = 0; of < 4; ++of)
#pragma unroll
      for (int nf = 0; nf < 4; ++nf)
        acc[of][nf] = MFMA16(a[of], b[nf], acc[of][nf]);
  }

#pragma unroll
  for (int of = 0; of < 4; ++of) {
    int orow = o0 + wr * 64 + of * 16 + kg * 4;
    f32x4 sh = *(const f32x4*)(shift + orow);
#pragma unroll
    for (int nf = 0; nf < 4; ++nf) {
      int n = n0 + wc * 64 + nf * 16 + fm;
      f16x4 st;
#pragma unroll
      for (int r = 0; r < 4; ++r)
        st[r] = (f16)fmaxf(acc[of][nf][r] + sh[r], 0.0f);
      *(f16x4*)(out + (size_t)n * C + orow) = st;
    }
  }
}

// ---------------- depthwise xcorr, row-per-wave with register reuse ----------------
__global__ __launch_bounds__(256) void xcorr_dw_row(
    const f16* __restrict__ S /* [128][31][31][256] */,
    const f16* __restrict__ K /* [128][7][7][256] */,
    f16* __restrict__ F /* [128][25][25][256] */) {
  int id = blockIdx.x;            // 0..895, XCD-swizzled
  int x = id & 7;
  int r = id >> 3;
  int g = r % 7;
  int bq = r / 7;
  int b = bq * 8 + x;

  int wave = threadIdx.x >> 6;
  int lane = threadIdx.x & 63;
  int oi = g * 4 + wave;          // 0..27
  if (oi >= 25) return;

  const f16* Sb = S + (size_t)b * 961 * 256 + lane * 4;
  const f16* Kb = K + (size_t)b * 49 * 256 + lane * 4;

  f32x4 acc[25] = {};

  for (int di = 0; di < 7; ++di) {
    const f16* sp = Sb + (size_t)(oi + di) * 31 * 256;
    f16x4 srow[31];
#pragma unroll
    for (int j = 0; j < 31; ++j) srow[j] = *(const f16x4*)(sp + (size_t)j * 256);
    const f16* kp = Kb + (size_t)di * 7 * 256;
    f16x4 krow[7];
#pragma unroll
    for (int j = 0; j < 7; ++j) krow[j] = *(const f16x4*)(kp + (size_t)j * 256);

#pragma unroll
    for (int dj = 0; dj < 7; ++dj) {
      float k0 = (float)krow[dj][0];
      float k1 = (float)krow[dj][1];
      float k2 = (float)krow[dj][2];
      float k3 = (float)krow[dj][3];
#pragma unroll
      for (int oj = 0; oj < 25; ++oj) {
        f16x4 sv = srow[oj + dj];
        acc[oj][0] += (float)sv[0] * k0;
        acc[oj][1] += (float)sv[1] * k1;
        acc[oj][2] += (float)sv[2] * k2;
        acc[oj][3] += (float)sv[3] * k3;
      }
    }
  }

  f16* Fb = F + ((size_t)b * 625 + (size_t)oi * 25) * 256 + lane * 4;
#pragma unroll
  for (int oj = 0; oj < 25; ++oj) {
    f16x4 o;
#pragma unroll
    for (int e = 0; e < 4; ++e) o[e] = (f16)acc[oj][e];
    *(f16x4*)(Fb + (size_t)oj * 256) = o;
  }
}

// ---------------- fused head: conv1(256->256)+BN+ReLU then conv2(256->20)+bias ----------
__global__ __launch_bounds__(256) void head_fused(
    const f16* __restrict__ Xt /* feat [80000][256] */,
    const f16* __restrict__ W1, const float* __restrict__ shift,
    const f16* __restrict__ W2p /* [32][256] */, const float* __restrict__ bias,
    float* __restrict__ out /* [128][20][625] */) {
  const int C = 256;
  int n0 = blockIdx.x * 64;
  int t = threadIdx.x;
  int lane = t & 63, wave = t >> 6;
  int fm = lane & 15, kg = lane >> 4;

  __shared__ f16 Ys[32][64][8];   // y-tile chunk-major

  const f16* wp = W1 + (size_t)(wave * 64 + fm) * C + kg * 8;
  const f16* xp = Xt + (size_t)(n0 + fm) * C + kg * 8;

  f32x4 acc[4][4] = {};
#pragma unroll
  for (int c0 = 0; c0 < 256; c0 += 32) {
    f16x8 a[4], b[4];
#pragma unroll
    for (int of = 0; of < 4; ++of) a[of] = *(const f16x8*)(wp + (size_t)of * 16 * C + c0);
#pragma unroll
    for (int nf = 0; nf < 4; ++nf) b[nf] = *(const f16x8*)(xp + (size_t)nf * 16 * C + c0);
#pragma unroll
    for (int of = 0; of < 4; ++of)
#pragma unroll
      for (int nf = 0; nf < 4; ++nf)
        acc[of][nf] = MFMA16(a[of], b[nf], acc[of][nf]);
  }

#pragma unroll
  for (int of = 0; of < 4; ++of) {
    int orow = wave * 64 + of * 16 + kg * 4;
#pragma unroll
    for (int nf = 0; nf < 4; ++nf) {
      int n = nf * 16 + fm;
      f16x4 st;
#pragma unroll
      for (int r = 0; r < 4; ++r)
        st[r] = (f16)fmaxf(acc[of][nf][r] + shift[orow + r], 0.0f);
      *(f16x4*)&Ys[orow >> 3][n][(kg & 1) * 4] = st;
    }
  }
  __syncthreads();

  // GEMM2: M=32 (20 live), N=64 (wave -> 16 n), K=256
  f32x4 acc2[2] = {};
#pragma unroll
  for (int c0 = 0; c0 < 256; c0 += 32) {
    f16x8 b = *(const f16x8*)&Ys[(c0 >> 3) + kg][wave * 16 + fm][0];
    f16x8 a0 = *(const f16x8*)(W2p + (size_t)fm * C + c0 + kg * 8);
    f16x8 a1 = *(const f16x8*)(W2p + (size_t)(16 + fm) * C + c0 + kg * 8);
    acc2[0] = MFMA16(a0, b, acc2[0]);
    acc2[1] = MFMA16(a1, b, acc2[1]);
  }

  int n = n0 + wave * 16 + fm;
  int bq = n / 625, bp = n - bq * 625;
  float* op = out + (size_t)bq * 12500 + bp;
#pragma unroll
  for (int of = 0; of < 2; ++of) {
#pragma unroll
    for (int r = 0; r < 4; ++r) {
      int o = of * 16 + kg * 4 + r;
      if (o < 20) op[(size_t)o * 625] = acc2[of][r] + bias[o];
    }
  }
}

extern "C" void kernel_launch(void* const* d_in, const int* in_sizes, int n_in,
                              void* d_out, int out_size, void* d_ws, size_t ws_size,
                              hipStream_t stream) {
  const float* kernel_in = (const float*)d_in[0];
  const float* search    = (const float*)d_in[1];
  const float* w_k = (const float*)d_in[2];
  const float* g_k = (const float*)d_in[3];
  const float* b_k = (const float*)d_in[4];
  const float* m_k = (const float*)d_in[5];
  const float* v_k = (const float*)d_in[6];
  const float* w_s = (const float*)d_in[7];
  const float* g_s = (const float*)d_in[8];
  const float* b_s = (const float*)d_in[9];
  const float* m_s = (const float*)d_in[10];
  const float* v_s = (const float*)d_in[11];
  const float* w_h1 = (const float*)d_in[12];
  const float* g_h = (const float*)d_in[13];
  const float* b_h = (const float*)d_in[14];
  const float* m_h = (const float*)d_in[15];
  const float* v_h = (const float*)d_in[16];
  const float* w_h2 = (const float*)d_in[17];
  const float* bias_h2 = (const float*)d_in[18];
  float* out = (float*)d_out;

  char* ws = (char*)d_ws;
  f16* wk16  = (f16*)(ws + OFF_WK);
  f16* ws16  = (f16*)(ws + OFF_WS);
  f16* wh116 = (f16*)(ws + OFF_WH1);
  f16* w2p   = (f16*)(ws + OFF_W2P);
  float* shifts = (float*)(ws + OFF_SH);
  f16* xts  = (f16*)(ws + OFF_S);     // transposed search input
  f16* xtk  = (f16*)(ws + OFF_KF);    // transposed kernel input
  f16* fbuf = (f16*)(ws + OFF_FEAT);
  f16* sbuf = (f16*)(ws + OFF_S2);    // search features
  f16* kbuf = (f16*)(ws + OFF_KF2);   // kernel features

  prep_weights<<<256, 256, 0, stream>>>(w_k, g_k, b_k, m_k, v_k,
                                        w_s, g_s, b_s, m_s, v_s,
                                        w_h1, g_h, b_h, m_h, v_h, w_h2,
                                        wk16, ws16, wh116, w2p, shifts);

  // streaming NCHW->channels-last f16 transposes
  transpose_cl<961><<<dim3(8, 4, 128), 256, 0, stream>>>(search, xts);
  transpose_cl<49><<<dim3(1, 4, 128), 256, 0, stream>>>(kernel_in, xtk);

  // LDS GEMMs: 128n x 128o tiles, 2 o-halves per n-tile
  gemm_lds<<<dim3(1922), 256, 0, stream>>>(xts, ws16, shifts + 256, sbuf);
  gemm_lds<<<dim3(98), 256, 0, stream>>>(xtk, wk16, shifts + 0, kbuf);

  // depthwise xcorr
  xcorr_dw_row<<<dim3(896), 256, 0, stream>>>(sbuf, kbuf, fbuf);

  // fused head: conv1+BN+ReLU+conv2+bias -> fp32 NCHW
  head_fused<<<dim3(1250), 256, 0, stream>>>(
      fbuf, wh116, shifts + 512, w2p, bias_h2, out);
}

// Round 9
// 175.233 us; speedup vs baseline: 1.2347x; 1.0901x over previous
//
#include <hip/hip_runtime.h>
#include <hip/hip_fp16.h>

typedef _Float16 f16;
typedef __attribute__((ext_vector_type(8))) _Float16 f16x8;
typedef __attribute__((ext_vector_type(4))) _Float16 f16x4;
typedef __attribute__((ext_vector_type(2))) _Float16 f16x2;
typedef __attribute__((ext_vector_type(4))) float f32x4;

#define MFMA16(a, b, c) __builtin_amdgcn_mfma_f32_16x16x32_f16((a), (b), (c), 0, 0, 0)

// ---------------- workspace layout (bytes) ----------------
#define OFF_WK   0u              // w_k folded f16 [256][256]
#define OFF_WS   131072u         // w_s folded f16 [256][256]
#define OFF_WH1  262144u         // w_h1 folded f16 [256][256]
#define OFF_W2P  393216u         // w_h2 padded f16 [32][256]
#define OFF_SH   409600u         // shifts f32 [3][256]
#define OFF_S    412672u         // s feat f16 [123008][256]
#define OFF_KF   63392768u       // k feat f16 [6272][256]
#define OFF_FEAT 66604032u       // xcorr out f16 [80000][256]

// ---------------- weight prep: fold BN scale, convert to f16, pad W2 ----------------
__global__ __launch_bounds__(256) void prep_weights(
    const float* __restrict__ wk, const float* __restrict__ gk, const float* __restrict__ bk,
    const float* __restrict__ mk, const float* __restrict__ vk,
    const float* __restrict__ wsr, const float* __restrict__ gs, const float* __restrict__ bs,
    const float* __restrict__ ms, const float* __restrict__ vs,
    const float* __restrict__ wh1, const float* __restrict__ gh, const float* __restrict__ bh,
    const float* __restrict__ mh, const float* __restrict__ vh,
    const float* __restrict__ wh2,
    f16* __restrict__ wk16, f16* __restrict__ ws16, f16* __restrict__ wh116,
    f16* __restrict__ w2p, float* __restrict__ shifts) {
  int o = blockIdx.x;
  int t = threadIdx.x;
  float sck = gk[o] * rsqrtf(vk[o] + 1e-5f);
  float scs = gs[o] * rsqrtf(vs[o] + 1e-5f);
  float sch = gh[o] * rsqrtf(vh[o] + 1e-5f);
  int idx = o * 256 + t;
  wk16[idx]  = (f16)(wk[idx] * sck);
  ws16[idx]  = (f16)(wsr[idx] * scs);
  wh116[idx] = (f16)(wh1[idx] * sch);
  if (o < 32) w2p[idx] = (o < 20) ? (f16)wh2[idx] : (f16)0;
  if (t == 0) {
    shifts[o]       = bk[o] - mk[o] * sck;
    shifts[256 + o] = bs[o] - ms[o] * scs;
    shifts[512 + o] = bh[o] - mh[o] * sch;
  }
}

// π row permutation: makes BOTH staged b32 writes (n-granularity 4) and b128
// fragment reads (n = lane&15) <=2-way bank-conflicted with 80 B row stride.
__device__ __forceinline__ int pi_row(int q, int r) {  // n = 4q + r
  return (q ^ (r << 2)) + (r << 4);
}

// ---------------- direct-NCHW conv1x1+BN+ReLU -> f16 [N][256] channels-last ----------
// Tile: 64 px x 256 o, BK=32, 8 K-steps, double-buffered LDS, one barrier/step.
// Staging per step/thread: 2 coalesced float4 (2 channel rows x 4 px, 256B runs),
// fp32->f16, register transpose, 4 ds_write_b32 into pi-permuted [64n][32k] tile.
// A (weights) per-step from global (L2-resident). No Xt intermediate.
template <int P>
__global__ __launch_bounds__(256) void conv_nchw(
    const float* __restrict__ X, const f16* __restrict__ W,
    const float* __restrict__ shift, f16* __restrict__ out) {
  const int C = 256;
  int n0 = blockIdx.x * 64;
  int t = threadIdx.x;
  int lane = t & 63, wave = t >> 6;
  int fm = lane & 15, kg = lane >> 4;

  __shared__ f16 Bs[2][64 * 40];   // row = pi(n), 40 f16 (80 B) per row; 10 KB total

  int b0 = n0 / P, bp0 = n0 - b0 * P;
  bool safe = (bp0 + 64 <= P);

  int px = (t & 15) * 4;           // local pixel base 0..60
  int cpr = (t >> 4) * 2;          // step-local channel pair 0,2,..,30
  const float* xb = X + ((size_t)b0 * C) * P + bp0 + px;   // + c*P per step (safe)

  int ub[4], up[4];
  if (!safe) {
#pragma unroll
    for (int e = 0; e < 4; ++e) {
      int gn = n0 + px + e;
      ub[e] = gn / P;
      up[e] = gn - ub[e] * P;
    }
  }

  // staged-write rows: n = px + e -> q = t&15, r = e
  int wrow[4];
#pragma unroll
  for (int e = 0; e < 4; ++e) wrow[e] = pi_row(t & 15, e);

  // fragment-read rows: n = nf*16 + fm -> q = nf*4 + (fm>>2), r = fm&3
  int rrow[4];
#pragma unroll
  for (int nf = 0; nf < 4; ++nf) rrow[nf] = pi_row(nf * 4 + (fm >> 2), fm & 3);

  const f16* wp = W + (size_t)(wave * 64 + fm) * C + kg * 8;

  // preload K-step 0
  f32x4 r0, r1;
  {
    int cl = cpr;
    if (safe) {
      r0 = *(const f32x4*)(xb + (size_t)cl * P);
      r1 = *(const f32x4*)(xb + (size_t)(cl + 1) * P);
    } else {
#pragma unroll
      for (int e = 0; e < 4; ++e) {
        r0[e] = X[((size_t)ub[e] * C + cl) * P + up[e]];
        r1[e] = X[((size_t)ub[e] * C + cl + 1) * P + up[e]];
      }
    }
  }

  f32x4 acc[4][4] = {};
#pragma unroll
  for (int ci = 0; ci < 8; ++ci) {
    f16* buf = Bs[ci & 1];
    // transpose + LDS write (f16x2 along k)
#pragma unroll
    for (int e = 0; e < 4; ++e) {
      f16x2 v;
      v[0] = (f16)r0[e];
      v[1] = (f16)r1[e];
      *(f16x2*)&buf[wrow[e] * 40 + cpr] = v;
    }
    // issue next step's loads before the barrier (latency hides under MFMA)
    if (ci < 7) {
      int cl = (ci + 1) * 32 + cpr;
      if (safe) {
        r0 = *(const f32x4*)(xb + (size_t)cl * P);
        r1 = *(const f32x4*)(xb + (size_t)(cl + 1) * P);
      } else {
#pragma unroll
        for (int e = 0; e < 4; ++e) {
          r0[e] = X[((size_t)ub[e] * C + cl) * P + up[e]];
          r1[e] = X[((size_t)ub[e] * C + cl + 1) * P + up[e]];
        }
      }
    }
    __syncthreads();

    f16x8 a[4], b[4];
#pragma unroll
    for (int of = 0; of < 4; ++of)
      a[of] = *(const f16x8*)(wp + (size_t)of * 16 * C + ci * 32);
#pragma unroll
    for (int nf = 0; nf < 4; ++nf)
      b[nf] = *(const f16x8*)&buf[rrow[nf] * 40 + kg * 8];
#pragma unroll
    for (int of = 0; of < 4; ++of)
#pragma unroll
      for (int nf = 0; nf < 4; ++nf)
        acc[of][nf] = MFMA16(a[of], b[nf], acc[of][nf]);
  }

#pragma unroll
  for (int of = 0; of < 4; ++of) {
    int orow = wave * 64 + of * 16 + kg * 4;
    f32x4 sh = *(const f32x4*)(shift + orow);
#pragma unroll
    for (int nf = 0; nf < 4; ++nf) {
      int n = n0 + nf * 16 + fm;
      f16x4 st;
#pragma unroll
      for (int r = 0; r < 4; ++r)
        st[r] = (f16)fmaxf(acc[of][nf][r] + sh[r], 0.0f);
      *(f16x4*)(out + (size_t)n * C + orow) = st;
    }
  }
}

// ---------------- depthwise xcorr, row-per-wave with register reuse ----------------
__global__ __launch_bounds__(256) void xcorr_dw_row(
    const f16* __restrict__ S /* [128][31][31][256] */,
    const f16* __restrict__ K /* [128][7][7][256] */,
    f16* __restrict__ F /* [128][25][25][256] */) {
  int id = blockIdx.x;            // 0..895, XCD-swizzled
  int x = id & 7;
  int r = id >> 3;
  int g = r % 7;
  int bq = r / 7;
  int b = bq * 8 + x;

  int wave = threadIdx.x >> 6;
  int lane = threadIdx.x & 63;
  int oi = g * 4 + wave;          // 0..27
  if (oi >= 25) return;

  const f16* Sb = S + (size_t)b * 961 * 256 + lane * 4;
  const f16* Kb = K + (size_t)b * 49 * 256 + lane * 4;

  f32x4 acc[25] = {};

  for (int di = 0; di < 7; ++di) {
    const f16* sp = Sb + (size_t)(oi + di) * 31 * 256;
    f16x4 srow[31];
#pragma unroll
    for (int j = 0; j < 31; ++j) srow[j] = *(const f16x4*)(sp + (size_t)j * 256);
    const f16* kp = Kb + (size_t)di * 7 * 256;
    f16x4 krow[7];
#pragma unroll
    for (int j = 0; j < 7; ++j) krow[j] = *(const f16x4*)(kp + (size_t)j * 256);

#pragma unroll
    for (int dj = 0; dj < 7; ++dj) {
      float k0 = (float)krow[dj][0];
      float k1 = (float)krow[dj][1];
      float k2 = (float)krow[dj][2];
      float k3 = (float)krow[dj][3];
#pragma unroll
      for (int oj = 0; oj < 25; ++oj) {
        f16x4 sv = srow[oj + dj];
        acc[oj][0] += (float)sv[0] * k0;
        acc[oj][1] += (float)sv[1] * k1;
        acc[oj][2] += (float)sv[2] * k2;
        acc[oj][3] += (float)sv[3] * k3;
      }
    }
  }

  f16* Fb = F + ((size_t)b * 625 + (size_t)oi * 25) * 256 + lane * 4;
#pragma unroll
  for (int oj = 0; oj < 25; ++oj) {
    f16x4 o;
#pragma unroll
    for (int e = 0; e < 4; ++e) o[e] = (f16)acc[oj][e];
    *(f16x4*)(Fb + (size_t)oj * 256) = o;
  }
}

// ---------------- fused head: conv1(256->256)+BN+ReLU then conv2(256->20)+bias ----------
__global__ __launch_bounds__(256) void head_fused(
    const f16* __restrict__ Xt /* feat [80000][256] */,
    const f16* __restrict__ W1, const float* __restrict__ shift,
    const f16* __restrict__ W2p /* [32][256] */, const float* __restrict__ bias,
    float* __restrict__ out /* [128][20][625] */) {
  const int C = 256;
  int n0 = blockIdx.x * 64;
  int t = threadIdx.x;
  int lane = t & 63, wave = t >> 6;
  int fm = lane & 15, kg = lane >> 4;

  __shared__ f16 Ys[32][64][8];   // y-tile chunk-major

  const f16* wp = W1 + (size_t)(wave * 64 + fm) * C + kg * 8;
  const f16* xp = Xt + (size_t)(n0 + fm) * C + kg * 8;

  f32x4 acc[4][4] = {};
#pragma unroll
  for (int c0 = 0; c0 < 256; c0 += 32) {
    f16x8 a[4], b[4];
#pragma unroll
    for (int of = 0; of < 4; ++of) a[of] = *(const f16x8*)(wp + (size_t)of * 16 * C + c0);
#pragma unroll
    for (int nf = 0; nf < 4; ++nf) b[nf] = *(const f16x8*)(xp + (size_t)nf * 16 * C + c0);
#pragma unroll
    for (int of = 0; of < 4; ++of)
#pragma unroll
      for (int nf = 0; nf < 4; ++nf)
        acc[of][nf] = MFMA16(a[of], b[nf], acc[of][nf]);
  }

#pragma unroll
  for (int of = 0; of < 4; ++of) {
    int orow = wave * 64 + of * 16 + kg * 4;
#pragma unroll
    for (int nf = 0; nf < 4; ++nf) {
      int n = nf * 16 + fm;
      f16x4 st;
#pragma unroll
      for (int r = 0; r < 4; ++r)
        st[r] = (f16)fmaxf(acc[of][nf][r] + shift[orow + r], 0.0f);
      *(f16x4*)&Ys[orow >> 3][n][(kg & 1) * 4] = st;
    }
  }
  __syncthreads();

  // GEMM2: M=32 (20 live), N=64 (wave -> 16 n), K=256
  f32x4 acc2[2] = {};
#pragma unroll
  for (int c0 = 0; c0 < 256; c0 += 32) {
    f16x8 b = *(const f16x8*)&Ys[(c0 >> 3) + kg][wave * 16 + fm][0];
    f16x8 a0 = *(const f16x8*)(W2p + (size_t)fm * C + c0 + kg * 8);
    f16x8 a1 = *(const f16x8*)(W2p + (size_t)(16 + fm) * C + c0 + kg * 8);
    acc2[0] = MFMA16(a0, b, acc2[0]);
    acc2[1] = MFMA16(a1, b, acc2[1]);
  }

  int n = n0 + wave * 16 + fm;
  int bq = n / 625, bp = n - bq * 625;
  float* op = out + (size_t)bq * 12500 + bp;
#pragma unroll
  for (int of = 0; of < 2; ++of) {
#pragma unroll
    for (int r = 0; r < 4; ++r) {
      int o = of * 16 + kg * 4 + r;
      if (o < 20) op[(size_t)o * 625] = acc2[of][r] + bias[o];
    }
  }
}

extern "C" void kernel_launch(void* const* d_in, const int* in_sizes, int n_in,
                              void* d_out, int out_size, void* d_ws, size_t ws_size,
                              hipStream_t stream) {
  const float* kernel_in = (const float*)d_in[0];
  const float* search    = (const float*)d_in[1];
  const float* w_k = (const float*)d_in[2];
  const float* g_k = (const float*)d_in[3];
  const float* b_k = (const float*)d_in[4];
  const float* m_k = (const float*)d_in[5];
  const float* v_k = (const float*)d_in[6];
  const float* w_s = (const float*)d_in[7];
  const float* g_s = (const float*)d_in[8];
  const float* b_s = (const float*)d_in[9];
  const float* m_s = (const float*)d_in[10];
  const float* v_s = (const float*)d_in[11];
  const float* w_h1 = (const float*)d_in[12];
  const float* g_h = (const float*)d_in[13];
  const float* b_h = (const float*)d_in[14];
  const float* m_h = (const float*)d_in[15];
  const float* v_h = (const float*)d_in[16];
  const float* w_h2 = (const float*)d_in[17];
  const float* bias_h2 = (const float*)d_in[18];
  float* out = (float*)d_out;

  char* ws = (char*)d_ws;
  f16* wk16  = (f16*)(ws + OFF_WK);
  f16* ws16  = (f16*)(ws + OFF_WS);
  f16* wh116 = (f16*)(ws + OFF_WH1);
  f16* w2p   = (f16*)(ws + OFF_W2P);
  float* shifts = (float*)(ws + OFF_SH);
  f16* sbuf = (f16*)(ws + OFF_S);     // search features
  f16* kbuf = (f16*)(ws + OFF_KF);    // kernel features
  f16* fbuf = (f16*)(ws + OFF_FEAT);

  prep_weights<<<256, 256, 0, stream>>>(w_k, g_k, b_k, m_k, v_k,
                                        w_s, g_s, b_s, m_s, v_s,
                                        w_h1, g_h, b_h, m_h, v_h, w_h2,
                                        wk16, ws16, wh116, w2p, shifts);

  // direct-NCHW fused transpose+GEMM: 64 px x 256 o per block
  conv_nchw<961><<<dim3(1922), 256, 0, stream>>>(search, ws16, shifts + 256, sbuf);
  conv_nchw<49><<<dim3(98), 256, 0, stream>>>(kernel_in, wk16, shifts + 0, kbuf);

  // depthwise xcorr
  xcorr_dw_row<<<dim3(896), 256, 0, stream>>>(sbuf, kbuf, fbuf);

  // fused head: conv1+BN+ReLU+conv2+bias -> fp32 NCHW
  head_fused<<<dim3(1250), 256, 0, stream>>>(
      fbuf, wh116, shifts + 512, w2p, bias_h2, out);
}

// Round 10
// 174.016 us; speedup vs baseline: 1.2434x; 1.0070x over previous
//
#include <hip/hip_runtime.h>
#include <hip/hip_fp16.h>

typedef _Float16 f16;
typedef __attribute__((ext_vector_type(8))) _Float16 f16x8;
typedef __attribute__((ext_vector_type(4))) _Float16 f16x4;
typedef __attribute__((ext_vector_type(2))) _Float16 f16x2;
typedef __attribute__((ext_vector_type(4))) float f32x4;

#define MFMA16(a, b, c) __builtin_amdgcn_mfma_f32_16x16x32_f16((a), (b), (c), 0, 0, 0)

// ---------------- workspace layout (bytes) ----------------
#define OFF_WK   0u              // w_k folded f16 [256][256]
#define OFF_WS   131072u         // w_s folded f16 [256][256]
#define OFF_WH1  262144u         // w_h1 folded f16 [256][256]
#define OFF_W2P  393216u         // w_h2 padded f16 [32][256]
#define OFF_SH   409600u         // shifts f32 [3][256]
#define OFF_S    412672u         // s feat f16 [123008][256]
#define OFF_KF   63392768u       // k feat f16 [6272][256]
#define OFF_FEAT 66604032u       // xcorr out f16 [80000][256]

// ---------------- weight prep: fold BN scale, convert to f16, pad W2 ----------------
__global__ __launch_bounds__(256) void prep_weights(
    const float* __restrict__ wk, const float* __restrict__ gk, const float* __restrict__ bk,
    const float* __restrict__ mk, const float* __restrict__ vk,
    const float* __restrict__ wsr, const float* __restrict__ gs, const float* __restrict__ bs,
    const float* __restrict__ ms, const float* __restrict__ vs,
    const float* __restrict__ wh1, const float* __restrict__ gh, const float* __restrict__ bh,
    const float* __restrict__ mh, const float* __restrict__ vh,
    const float* __restrict__ wh2,
    f16* __restrict__ wk16, f16* __restrict__ ws16, f16* __restrict__ wh116,
    f16* __restrict__ w2p, float* __restrict__ shifts) {
  int o = blockIdx.x;
  int t = threadIdx.x;
  float sck = gk[o] * rsqrtf(vk[o] + 1e-5f);
  float scs = gs[o] * rsqrtf(vs[o] + 1e-5f);
  float sch = gh[o] * rsqrtf(vh[o] + 1e-5f);
  int idx = o * 256 + t;
  wk16[idx]  = (f16)(wk[idx] * sck);
  ws16[idx]  = (f16)(wsr[idx] * scs);
  wh116[idx] = (f16)(wh1[idx] * sch);
  if (o < 32) w2p[idx] = (o < 20) ? (f16)wh2[idx] : (f16)0;
  if (t == 0) {
    shifts[o]       = bk[o] - mk[o] * sck;
    shifts[256 + o] = bs[o] - ms[o] * scs;
    shifts[512 + o] = bh[o] - mh[o] * sch;
  }
}

// π row permutation for LDS B-tile (same as R9)
__device__ __forceinline__ int pi_row(int q, int r) {  // n = 4q + r
  return (q ^ (r << 2)) + (r << 4);
}

// ---------------- direct-NCHW conv1x1+BN+ReLU -> f16 [N][256] channels-last ----------
// R10: counted-vmcnt pipeline.
//  * raw s_barrier + lgkmcnt(0) only (no vmcnt drain at barriers)
//  * 3-deep register prefetch of the B (HBM) staging loads, fully unrolled
//  * A (weights, L2) issued at top of each K-step
template <int P>
__global__ __launch_bounds__(256) void conv_nchw(
    const float* __restrict__ X, const f16* __restrict__ W,
    const float* __restrict__ shift, f16* __restrict__ out) {
  const int C = 256;
  int n0 = blockIdx.x * 64;
  int t = threadIdx.x;
  int lane = t & 63, wave = t >> 6;
  int fm = lane & 15, kg = lane >> 4;

  __shared__ f16 Bs[2][64 * 40];   // row = pi(n), 80 B per row

  int b0 = n0 / P, bp0 = n0 - b0 * P;
  bool safe = (bp0 + 64 <= P);

  int px = (t & 15) * 4;           // local pixel base
  int cpr = (t >> 4) * 2;          // step-local channel pair
  const float* xb = X + ((size_t)b0 * C) * P + bp0 + px;

  int ub[4], up[4];
  if (!safe) {
#pragma unroll
    for (int e = 0; e < 4; ++e) {
      int gn = n0 + px + e;
      ub[e] = gn / P;
      up[e] = gn - ub[e] * P;
    }
  }

  int wrow[4];
#pragma unroll
  for (int e = 0; e < 4; ++e) wrow[e] = pi_row(t & 15, e);
  int rrow[4];
#pragma unroll
  for (int nf = 0; nf < 4; ++nf) rrow[nf] = pi_row(nf * 4 + (fm >> 2), fm & 3);

  const f16* wp = W + (size_t)(wave * 64 + fm) * C + kg * 8;

  // ---- 3-deep B prefetch ring ----
  f32x4 rb[3][2];
#pragma unroll
  for (int s = 0; s < 3; ++s) {
    int cl = s * 32 + cpr;
    if (safe) {
      rb[s][0] = *(const f32x4*)(xb + (size_t)cl * P);
      rb[s][1] = *(const f32x4*)(xb + (size_t)(cl + 1) * P);
    } else {
#pragma unroll
      for (int e = 0; e < 4; ++e) {
        rb[s][0][e] = X[((size_t)ub[e] * C + cl) * P + up[e]];
        rb[s][1][e] = X[((size_t)ub[e] * C + cl + 1) * P + up[e]];
      }
    }
  }

  f32x4 acc[4][4] = {};
#pragma unroll
  for (int ci = 0; ci < 8; ++ci) {
    // A loads for this step (L2); consumed after the barrier -> counted vmcnt cover
    f16x8 a[4];
#pragma unroll
    for (int of = 0; of < 4; ++of)
      a[of] = *(const f16x8*)(wp + (size_t)of * 16 * C + ci * 32);

    f16* buf = Bs[ci & 1];
    // transpose + LDS write from ring slot ci%3 (compiler waits counted vmcnt)
#pragma unroll
    for (int e = 0; e < 4; ++e) {
      f16x2 v;
      v[0] = (f16)rb[ci % 3][0][e];
      v[1] = (f16)rb[ci % 3][1][e];
      *(f16x2*)&buf[wrow[e] * 40 + cpr] = v;
    }
    // refill ring slot with step ci+3 (stays in flight across barriers)
    if (ci + 3 < 8) {
      int cl = (ci + 3) * 32 + cpr;
      if (safe) {
        rb[ci % 3][0] = *(const f32x4*)(xb + (size_t)cl * P);
        rb[ci % 3][1] = *(const f32x4*)(xb + (size_t)(cl + 1) * P);
      } else {
#pragma unroll
        for (int e = 0; e < 4; ++e) {
          rb[ci % 3][0][e] = X[((size_t)ub[e] * C + cl) * P + up[e]];
          rb[ci % 3][1][e] = X[((size_t)ub[e] * C + cl + 1) * P + up[e]];
        }
      }
    }
    // LDS-visibility barrier WITHOUT vmcnt drain
    asm volatile("s_waitcnt lgkmcnt(0)" ::: "memory");
    __builtin_amdgcn_s_barrier();

    f16x8 b[4];
#pragma unroll
    for (int nf = 0; nf < 4; ++nf)
      b[nf] = *(const f16x8*)&buf[rrow[nf] * 40 + kg * 8];
#pragma unroll
    for (int of = 0; of < 4; ++of)
#pragma unroll
      for (int nf = 0; nf < 4; ++nf)
        acc[of][nf] = MFMA16(a[of], b[nf], acc[of][nf]);
  }

#pragma unroll
  for (int of = 0; of < 4; ++of) {
    int orow = wave * 64 + of * 16 + kg * 4;
    f32x4 sh = *(const f32x4*)(shift + orow);
#pragma unroll
    for (int nf = 0; nf < 4; ++nf) {
      int n = n0 + nf * 16 + fm;
      f16x4 st;
#pragma unroll
      for (int r = 0; r < 4; ++r)
        st[r] = (f16)fmaxf(acc[of][nf][r] + sh[r], 0.0f);
      *(f16x4*)(out + (size_t)n * C + orow) = st;
    }
  }
}

// ---------------- depthwise xcorr, row-per-wave with register reuse ----------------
__global__ __launch_bounds__(256) void xcorr_dw_row(
    const f16* __restrict__ S /* [128][31][31][256] */,
    const f16* __restrict__ K /* [128][7][7][256] */,
    f16* __restrict__ F /* [128][25][25][256] */) {
  int id = blockIdx.x;            // 0..895, XCD-swizzled
  int x = id & 7;
  int r = id >> 3;
  int g = r % 7;
  int bq = r / 7;
  int b = bq * 8 + x;

  int wave = threadIdx.x >> 6;
  int lane = threadIdx.x & 63;
  int oi = g * 4 + wave;          // 0..27
  if (oi >= 25) return;

  const f16* Sb = S + (size_t)b * 961 * 256 + lane * 4;
  const f16* Kb = K + (size_t)b * 49 * 256 + lane * 4;

  f32x4 acc[25] = {};

  for (int di = 0; di < 7; ++di) {
    const f16* sp = Sb + (size_t)(oi + di) * 31 * 256;
    f16x4 srow[31];
#pragma unroll
    for (int j = 0; j < 31; ++j) srow[j] = *(const f16x4*)(sp + (size_t)j * 256);
    const f16* kp = Kb + (size_t)di * 7 * 256;
    f16x4 krow[7];
#pragma unroll
    for (int j = 0; j < 7; ++j) krow[j] = *(const f16x4*)(kp + (size_t)j * 256);

#pragma unroll
    for (int dj = 0; dj < 7; ++dj) {
      float k0 = (float)krow[dj][0];
      float k1 = (float)krow[dj][1];
      float k2 = (float)krow[dj][2];
      float k3 = (float)krow[dj][3];
#pragma unroll
      for (int oj = 0; oj < 25; ++oj) {
        f16x4 sv = srow[oj + dj];
        acc[oj][0] += (float)sv[0] * k0;
        acc[oj][1] += (float)sv[1] * k1;
        acc[oj][2] += (float)sv[2] * k2;
        acc[oj][3] += (float)sv[3] * k3;
      }
    }
  }

  f16* Fb = F + ((size_t)b * 625 + (size_t)oi * 25) * 256 + lane * 4;
#pragma unroll
  for (int oj = 0; oj < 25; ++oj) {
    f16x4 o;
#pragma unroll
    for (int e = 0; e < 4; ++e) o[e] = (f16)acc[oj][e];
    *(f16x4*)(Fb + (size_t)oj * 256) = o;
  }
}

// ---------------- fused head: conv1(256->256)+BN+ReLU then conv2(256->20)+bias ----------
__global__ __launch_bounds__(256) void head_fused(
    const f16* __restrict__ Xt /* feat [80000][256] */,
    const f16* __restrict__ W1, const float* __restrict__ shift,
    const f16* __restrict__ W2p /* [32][256] */, const float* __restrict__ bias,
    float* __restrict__ out /* [128][20][625] */) {
  const int C = 256;
  int n0 = blockIdx.x * 64;
  int t = threadIdx.x;
  int lane = t & 63, wave = t >> 6;
  int fm = lane & 15, kg = lane >> 4;

  __shared__ f16 Ys[32][64][8];   // y-tile chunk-major

  const f16* wp = W1 + (size_t)(wave * 64 + fm) * C + kg * 8;
  const f16* xp = Xt + (size_t)(n0 + fm) * C + kg * 8;

  f32x4 acc[4][4] = {};
#pragma unroll
  for (int c0 = 0; c0 < 256; c0 += 32) {
    f16x8 a[4], b[4];
#pragma unroll
    for (int of = 0; of < 4; ++of) a[of] = *(const f16x8*)(wp + (size_t)of * 16 * C + c0);
#pragma unroll
    for (int nf = 0; nf < 4; ++nf) b[nf] = *(const f16x8*)(xp + (size_t)nf * 16 * C + c0);
#pragma unroll
    for (int of = 0; of < 4; ++of)
#pragma unroll
      for (int nf = 0; nf < 4; ++nf)
        acc[of][nf] = MFMA16(a[of], b[nf], acc[of][nf]);
  }

#pragma unroll
  for (int of = 0; of < 4; ++of) {
    int orow = wave * 64 + of * 16 + kg * 4;
#pragma unroll
    for (int nf = 0; nf < 4; ++nf) {
      int n = nf * 16 + fm;
      f16x4 st;
#pragma unroll
      for (int r = 0; r < 4; ++r)
        st[r] = (f16)fmaxf(acc[of][nf][r] + shift[orow + r], 0.0f);
      *(f16x4*)&Ys[orow >> 3][n][(kg & 1) * 4] = st;
    }
  }
  __syncthreads();

  // GEMM2: M=32 (20 live), N=64 (wave -> 16 n), K=256
  f32x4 acc2[2] = {};
#pragma unroll
  for (int c0 = 0; c0 < 256; c0 += 32) {
    f16x8 b = *(const f16x8*)&Ys[(c0 >> 3) + kg][wave * 16 + fm][0];
    f16x8 a0 = *(const f16x8*)(W2p + (size_t)fm * C + c0 + kg * 8);
    f16x8 a1 = *(const f16x8*)(W2p + (size_t)(16 + fm) * C + c0 + kg * 8);
    acc2[0] = MFMA16(a0, b, acc2[0]);
    acc2[1] = MFMA16(a1, b, acc2[1]);
  }

  int n = n0 + wave * 16 + fm;
  int bq = n / 625, bp = n - bq * 625;
  float* op = out + (size_t)bq * 12500 + bp;
#pragma unroll
  for (int of = 0; of < 2; ++of) {
#pragma unroll
    for (int r = 0; r < 4; ++r) {
      int o = of * 16 + kg * 4 + r;
      if (o < 20) op[(size_t)o * 625] = acc2[of][r] + bias[o];
    }
  }
}

extern "C" void kernel_launch(void* const* d_in, const int* in_sizes, int n_in,
                              void* d_out, int out_size, void* d_ws, size_t ws_size,
                              hipStream_t stream) {
  const float* kernel_in = (const float*)d_in[0];
  const float* search    = (const float*)d_in[1];
  const float* w_k = (const float*)d_in[2];
  const float* g_k = (const float*)d_in[3];
  const float* b_k = (const float*)d_in[4];
  const float* m_k = (const float*)d_in[5];
  const float* v_k = (const float*)d_in[6];
  const float* w_s = (const float*)d_in[7];
  const float* g_s = (const float*)d_in[8];
  const float* b_s = (const float*)d_in[9];
  const float* m_s = (const float*)d_in[10];
  const float* v_s = (const float*)d_in[11];
  const float* w_h1 = (const float*)d_in[12];
  const float* g_h = (const float*)d_in[13];
  const float* b_h = (const float*)d_in[14];
  const float* m_h = (const float*)d_in[15];
  const float* v_h = (const float*)d_in[16];
  const float* w_h2 = (const float*)d_in[17];
  const float* bias_h2 = (const float*)d_in[18];
  float* out = (float*)d_out;

  char* ws = (char*)d_ws;
  f16* wk16  = (f16*)(ws + OFF_WK);
  f16* ws16  = (f16*)(ws + OFF_WS);
  f16* wh116 = (f16*)(ws + OFF_WH1);
  f16* w2p   = (f16*)(ws + OFF_W2P);
  float* shifts = (float*)(ws + OFF_SH);
  f16* sbuf = (f16*)(ws + OFF_S);     // search features
  f16* kbuf = (f16*)(ws + OFF_KF);    // kernel features
  f16* fbuf = (f16*)(ws + OFF_FEAT);

  prep_weights<<<256, 256, 0, stream>>>(w_k, g_k, b_k, m_k, v_k,
                                        w_s, g_s, b_s, m_s, v_s,
                                        w_h1, g_h, b_h, m_h, v_h, w_h2,
                                        wk16, ws16, wh116, w2p, shifts);

  // direct-NCHW fused transpose+GEMM with counted-vmcnt pipeline
  conv_nchw<961><<<dim3(1922), 256, 0, stream>>>(search, ws16, shifts + 256, sbuf);
  conv_nchw<49><<<dim3(98), 256, 0, stream>>>(kernel_in, wk16, shifts + 0, kbuf);

  // depthwise xcorr
  xcorr_dw_row<<<dim3(896), 256, 0, stream>>>(sbuf, kbuf, fbuf);

  // fused head: conv1+BN+ReLU+conv2+bias -> fp32 NCHW
  head_fused<<<dim3(1250), 256, 0, stream>>>(
      fbuf, wh116, shifts + 512, w2p, bias_h2, out);
}